// Round 5
// baseline (920.932 us; speedup 1.0000x reference)
//
#include <hip/hip_runtime.h>

#define N    8192
#define DT   768
#define DO   512
#define BM   128
#define BN   128
#define TI   (N / BM)   // 64
#define TJ   (N / BN)   // 64

typedef __attribute__((ext_vector_type(8))) int    int32x8;
typedef __attribute__((ext_vector_type(4))) int    int32x4;
typedef __attribute__((ext_vector_type(4))) float  floatx4;

// async global->LDS, 16B per lane (global_load_lds_dwordx4)
__device__ inline void gl2lds16(const void* g, void* l) {
    __builtin_amdgcn_global_load_lds(
        (const __attribute__((address_space(1))) unsigned int*)g,
        (__attribute__((address_space(3))) unsigned int*)l, 16, 0, 0);
}

// ---------------- row-normalize fp32 -> fp8 e4m3 (one wave per row) ----------------
__global__ void norm_kernel(const float* __restrict__ X,
                            unsigned int* __restrict__ Xn, int D,
                            float* __restrict__ zero_me) {
    if (zero_me && blockIdx.x == 0 && threadIdx.x == 0) zero_me[0] = 0.0f;
    const int row  = blockIdx.x * 4 + (threadIdx.x >> 6);
    const int lane = threadIdx.x & 63;
    const float* xr = X + (size_t)row * D;
    float ss = 0.0f;
    for (int c = lane * 4; c < D; c += 256) {
        const floatx4 v = *(const floatx4*)(xr + c);
        ss += v[0] * v[0] + v[1] * v[1] + v[2] * v[2] + v[3] * v[3];
    }
    #pragma unroll
    for (int m = 32; m >= 1; m >>= 1) ss += __shfl_xor(ss, m);
    const float scale = 1.0f / fmaxf(sqrtf(ss), 1e-8f);
    unsigned int* outr = Xn + (size_t)row * (D / 4);
    for (int c = lane * 4; c < D; c += 256) {
        const floatx4 v = *(const floatx4*)(xr + c);
        const int lo = __builtin_amdgcn_cvt_pk_fp8_f32(v[0] * scale, v[1] * scale, 0, false);
        const int hi = __builtin_amdgcn_cvt_pk_fp8_f32(v[2] * scale, v[3] * scale, 0, false);
        outr[c >> 2] = (unsigned int)(lo & 0xFFFF) | ((unsigned int)hi << 16);
    }
}

// ---------------- fused dual MX-fp8 GEMM + softmax-stat tile kernel ----------------
// K=128 per mfma_scale (scales = 1.0) -> teacher 6 iters + student 4 iters.
// m97-style two-barrier K-loop: stage at top, waitcnt+barrier, frags+MFMA,
// barrier. Frag pressure kept low (af[4]=32 regs preloaded, bf streamed 8 regs
// at a time) so acc(64)+frags(40)+addr(~30) fits the (256,3) ~170-VGPR cap —
// R4's cross-restage liveness of 64 frag regs caused catastrophic spilling.
// partials layout: [2*TJ][N][5] floats (Zt, V, UA, Zo, WB) per (slot,row).
// LDS: sA 16K + sB 16K + sW 16K = 48 KB -> 3 blocks/CU.
__launch_bounds__(256, 3)
__global__ void fused_kernel(const unsigned char* __restrict__ Xt,
                             const unsigned char* __restrict__ Xo,
                             float* __restrict__ partials) {
    __shared__ unsigned char sA[BM * 128];   // 16 KB (one 128x128B tile)
    __shared__ unsigned char sB[BN * 128];   // 16 KB
    __shared__ unsigned int  sW[16 * 256];   // 16 KB packed fp8 weights

    const int t = threadIdx.x, lane = t & 63, w = t >> 6;
    const int wm = w >> 1, wn = w & 1;
    const int lr = lane & 15, lg = lane >> 4;

    const int bid = blockIdx.x;
    const int tj = (bid & 7) | ((bid >> 9) << 3);
    const int ti = (bid >> 3) & 63;
    const int i0 = ti * BM, j0 = tj * BN;

    // staging: chunk m = (w*4+h)*64 + lane; row=m>>3, kc=(m&7)^(row&7)
    const int kc = (lane & 7) ^ (lane >> 3);
    int offT[4], offO[4], ldsOff[4];
    #pragma unroll
    for (int h = 0; h < 4; ++h) {
        const int row = (w * 4 + h) * 8 + (lane >> 3);
        offT[h]   = row * DT + kc * 16;
        offO[h]   = row * DO + kc * 16;
        ldsOff[h] = ((w * 4 + h) * 64 + lane) * 16;
    }
    const unsigned char* At = Xt + (size_t)i0 * DT;
    const unsigned char* Bt = Xt + (size_t)j0 * DT;
    const unsigned char* Ao = Xo + (size_t)i0 * DO;
    const unsigned char* Bo = Xo + (size_t)j0 * DO;

    // fragment ds_read addresses (loop-invariant); XOR swizzle: chunk^(row&7)
    int aoff[4][2], boff[4][2];
    #pragma unroll
    for (int mi = 0; mi < 4; ++mi) {
        const int rowA = wm * 64 + mi * 16 + lr;
        const int rowB = wn * 64 + mi * 16 + lr;
        #pragma unroll
        for (int s = 0; s < 2; ++s) {
            const int cc = ((lg * 2 + s) ^ (lr & 7)) * 16;
            aoff[mi][s] = rowA * 128 + cc;
            boff[mi][s] = rowB * 128 + cc;
        }
    }

    floatx4 acc[4][4];
    #pragma unroll
    for (int a = 0; a < 4; ++a)
        #pragma unroll
        for (int b = 0; b < 4; ++b)
            acc[a][b] = (floatx4){0.0f, 0.0f, 0.0f, 0.0f};

    // ---- teacher loop: 6 iterations of K=128 ----
    for (int kt = 0; kt < DT / 128; ++kt) {
        const int k0 = kt * 128;
        #pragma unroll
        for (int h = 0; h < 4; ++h) {
            gl2lds16(At + offT[h] + k0, sA + ldsOff[h]);
            gl2lds16(Bt + offT[h] + k0, sB + ldsOff[h]);
        }
        asm volatile("s_waitcnt vmcnt(0)" ::: "memory");
        __syncthreads();
        int32x8 af[4];
        #pragma unroll
        for (int mi = 0; mi < 4; ++mi) {
            union { int32x8 v; int32x4 q[2]; } ua;
            ua.q[0] = *(const int32x4*)(sA + aoff[mi][0]);
            ua.q[1] = *(const int32x4*)(sA + aoff[mi][1]);
            af[mi] = ua.v;
        }
        #pragma unroll
        for (int ni = 0; ni < 4; ++ni) {
            union { int32x8 v; int32x4 q[2]; } ub;
            ub.q[0] = *(const int32x4*)(sB + boff[ni][0]);
            ub.q[1] = *(const int32x4*)(sB + boff[ni][1]);
            #pragma unroll
            for (int mi = 0; mi < 4; ++mi)
                acc[mi][ni] = __builtin_amdgcn_mfma_scale_f32_16x16x128_f8f6f4(
                    af[mi], ub.v, acc[mi][ni],
                    0, 0,                      // cbsz=fp8, blgp=fp8
                    0, 0x7F7F7F7F,             // scale_a = 1.0 (e8m0 127)
                    0, 0x7F7F7F7F);            // scale_b = 1.0
        }
        __syncthreads();                       // frag reads done -> restage OK
    }

    // ---- teacher epilogue: Zt, V, UA per row; park W=e^3 as fp8 in sW ----
    // C/D layout (16x16 family, shape-determined): col=lane&15, row=lg*4+reg
    #pragma unroll
    for (int mi = 0; mi < 4; ++mi) {
        #pragma unroll
        for (int r = 0; r < 4; ++r) {
            const int row = wm * 64 + mi * 16 + lg * 4 + r;
            const int gi  = i0 + row;
            float zt = 0.0f, vv = 0.0f, ua = 0.0f, e3v[4];
            #pragma unroll
            for (int ni = 0; ni < 4; ++ni) {
                const int gj = j0 + wn * 64 + ni * 16 + lr;
                const float a = acc[mi][ni][r];
                float ea = __expf(a - 1.0f);
                if (gi == gj) ea = 0.0f;       // diagonal -> prob 0
                const float e3 = ea * ea * ea;
                zt += ea; vv += e3; ua += e3 * a; e3v[ni] = e3;
            }
            const int lo = __builtin_amdgcn_cvt_pk_fp8_f32(e3v[0], e3v[1], 0, false);
            const int hi = __builtin_amdgcn_cvt_pk_fp8_f32(e3v[2], e3v[3], 0, false);
            sW[(mi * 4 + r) * 256 + t] =
                (unsigned int)(lo & 0xFFFF) | ((unsigned int)hi << 16);
            #pragma unroll
            for (int m = 8; m >= 1; m >>= 1) {
                zt += __shfl_xor(zt, m);
                vv += __shfl_xor(vv, m);
                ua += __shfl_xor(ua, m);
            }
            if (lr == 0) {
                float* p = partials + ((size_t)(tj * 2 + wn) * N + gi) * 5;
                p[0] = zt; p[1] = vv; p[2] = ua;
            }
        }
    }

    // ---- student loop: 4 iterations of K=128 (same accumulators) ----
    #pragma unroll
    for (int a = 0; a < 4; ++a)
        #pragma unroll
        for (int b = 0; b < 4; ++b)
            acc[a][b] = (floatx4){0.0f, 0.0f, 0.0f, 0.0f};

    for (int ko = 0; ko < DO / 128; ++ko) {
        const int k0 = ko * 128;
        #pragma unroll
        for (int h = 0; h < 4; ++h) {
            gl2lds16(Ao + offO[h] + k0, sA + ldsOff[h]);
            gl2lds16(Bo + offO[h] + k0, sB + ldsOff[h]);
        }
        asm volatile("s_waitcnt vmcnt(0)" ::: "memory");
        __syncthreads();
        int32x8 af[4];
        #pragma unroll
        for (int mi = 0; mi < 4; ++mi) {
            union { int32x8 v; int32x4 q[2]; } ua;
            ua.q[0] = *(const int32x4*)(sA + aoff[mi][0]);
            ua.q[1] = *(const int32x4*)(sA + aoff[mi][1]);
            af[mi] = ua.v;
        }
        #pragma unroll
        for (int ni = 0; ni < 4; ++ni) {
            union { int32x8 v; int32x4 q[2]; } ub;
            ub.q[0] = *(const int32x4*)(sB + boff[ni][0]);
            ub.q[1] = *(const int32x4*)(sB + boff[ni][1]);
            #pragma unroll
            for (int mi = 0; mi < 4; ++mi)
                acc[mi][ni] = __builtin_amdgcn_mfma_scale_f32_16x16x128_f8f6f4(
                    af[mi], ub.v, acc[mi][ni],
                    0, 0, 0, 0x7F7F7F7F, 0, 0x7F7F7F7F);
        }
        __syncthreads();
    }

    // ---- student epilogue: Zo, WB per row ----
    #pragma unroll
    for (int mi = 0; mi < 4; ++mi) {
        #pragma unroll
        for (int r = 0; r < 4; ++r) {
            const int row = wm * 64 + mi * 16 + lg * 4 + r;
            const int gi  = i0 + row;
            const int w4  = (int)sW[(mi * 4 + r) * 256 + t];
            // byte-select must be an immediate: decode all four up front
            float wv[4];
            wv[0] = __builtin_amdgcn_cvt_f32_fp8(w4, 0);
            wv[1] = __builtin_amdgcn_cvt_f32_fp8(w4, 1);
            wv[2] = __builtin_amdgcn_cvt_f32_fp8(w4, 2);
            wv[3] = __builtin_amdgcn_cvt_f32_fp8(w4, 3);
            float zo = 0.0f, wb = 0.0f;
            #pragma unroll
            for (int ni = 0; ni < 4; ++ni) {
                const int gj = j0 + wn * 64 + ni * 16 + lr;
                const float b = acc[mi][ni][r];
                float eb = __expf(b - 1.0f);
                if (gi == gj) eb = 0.0f;
                zo += eb; wb += wv[ni] * b;    // diag: W==0 -> no contribution
            }
            #pragma unroll
            for (int m = 8; m >= 1; m >>= 1) {
                zo += __shfl_xor(zo, m);
                wb += __shfl_xor(wb, m);
            }
            if (lr == 0) {
                float* p = partials + ((size_t)(tj * 2 + wn) * N + gi) * 5;
                p[3] = zo; p[4] = wb;
            }
        }
    }
}

// ---------------- final per-row combine + scalar reduce ----------------
__global__ void reduce_kernel(const float* __restrict__ partials,
                              float* __restrict__ out) {
    const int i = blockIdx.x * 256 + threadIdx.x;   // row
    float zt = 0.0f, vv = 0.0f, ua = 0.0f, zo = 0.0f, wb = 0.0f;
    for (int jb = 0; jb < 2 * TJ; ++jb) {
        const float* p = partials + ((size_t)jb * N + i) * 5;
        zt += p[0]; vv += p[1]; ua += p[2]; zo += p[3]; wb += p[4];
    }
    // loss_i = (U + V*log(Zo/Zt)) / Zt^3, U = UA - WB
    float li = (ua - wb + vv * __logf(zo / zt)) / (zt * zt * zt);
    #pragma unroll
    for (int m = 32; m >= 1; m >>= 1) li += __shfl_xor(li, m);
    __shared__ float wsh[4];
    const int w = threadIdx.x >> 6;
    if ((threadIdx.x & 63) == 0) wsh[w] = li;
    __syncthreads();
    if (threadIdx.x == 0) {
        const float s = (wsh[0] + wsh[1] + wsh[2] + wsh[3]) *
                        (1.0f / ((float)N * (float)N));   // WEIGHT=1, mean over N^2
        atomicAdd(out, s);
    }
}

extern "C" void kernel_launch(void* const* d_in, const int* in_sizes, int n_in,
                              void* d_out, int out_size, void* d_ws, size_t ws_size,
                              hipStream_t stream) {
    (void)in_sizes; (void)n_in; (void)out_size; (void)ws_size;
    const float* mo = (const float*)d_in[0];   // model_output [8192,512] fp32
    const float* tg = (const float*)d_in[1];   // targets      [8192,768] fp32
    float* out = (float*)d_out;

    char* ws = (char*)d_ws;
    unsigned char* Xt = (unsigned char*)ws;                        // 8192*768 fp8 = 6.29 MB
    unsigned char* Xo = (unsigned char*)(ws + (size_t)N * DT);     // 8192*512 fp8 = 4.19 MB
    float* partials   = (float*)(ws + (size_t)N * DT + (size_t)N * DO);
    // partials: 128 * 8192 * 5 * 4 B = 20.97 MB; total ws ~31.5 MB

    norm_kernel<<<N / 4, 256, 0, stream>>>(tg, (unsigned int*)Xt, DT, out);  // also zeroes out
    norm_kernel<<<N / 4, 256, 0, stream>>>(mo, (unsigned int*)Xo, DO, nullptr);
    fused_kernel<<<TI * TJ, 256, 0, stream>>>(Xt, Xo, partials);
    reduce_kernel<<<N / 256, 256, 0, stream>>>(partials, out);
}

// Round 6
// 911.963 us; speedup vs baseline: 1.0098x; 1.0098x over previous
//
#include <hip/hip_runtime.h>

#define N    8192
#define DT   768
#define DO   512
#define BM   128
#define BN   128
#define TI   (N / BM)   // 64
#define TJ   (N / BN)   // 64

typedef __attribute__((ext_vector_type(8))) int    int32x8;
typedef __attribute__((ext_vector_type(4))) int    int32x4;
typedef __attribute__((ext_vector_type(4))) float  floatx4;

// async global->LDS, 16B per lane (global_load_lds_dwordx4)
__device__ inline void gl2lds16(const void* g, void* l) {
    __builtin_amdgcn_global_load_lds(
        (const __attribute__((address_space(1))) unsigned int*)g,
        (__attribute__((address_space(3))) unsigned int*)l, 16, 0, 0);
}

// register-only concat of two 16B LDS loads into one 32B frag (NO union:
// union type-punning defeats SROA -> stack -> 1.7 GB scratch traffic in R4/R5)
__device__ inline int32x8 frag32(const unsigned char* base, int off0, int off1) {
    const int32x4 lo = *(const int32x4*)(base + off0);
    const int32x4 hi = *(const int32x4*)(base + off1);
    return __builtin_shufflevector(lo, hi, 0, 1, 2, 3, 4, 5, 6, 7);
}

// ---------------- row-normalize fp32 -> fp8 e4m3 (one wave per row) ----------------
__global__ void norm_kernel(const float* __restrict__ X,
                            unsigned int* __restrict__ Xn, int D,
                            float* __restrict__ zero_me) {
    if (zero_me && blockIdx.x == 0 && threadIdx.x == 0) zero_me[0] = 0.0f;
    const int row  = blockIdx.x * 4 + (threadIdx.x >> 6);
    const int lane = threadIdx.x & 63;
    const float* xr = X + (size_t)row * D;
    float ss = 0.0f;
    for (int c = lane * 4; c < D; c += 256) {
        const floatx4 v = *(const floatx4*)(xr + c);
        ss += v[0] * v[0] + v[1] * v[1] + v[2] * v[2] + v[3] * v[3];
    }
    #pragma unroll
    for (int m = 32; m >= 1; m >>= 1) ss += __shfl_xor(ss, m);
    const float scale = 1.0f / fmaxf(sqrtf(ss), 1e-8f);
    unsigned int* outr = Xn + (size_t)row * (D / 4);
    for (int c = lane * 4; c < D; c += 256) {
        const floatx4 v = *(const floatx4*)(xr + c);
        const int lo = __builtin_amdgcn_cvt_pk_fp8_f32(v[0] * scale, v[1] * scale, 0, false);
        const int hi = __builtin_amdgcn_cvt_pk_fp8_f32(v[2] * scale, v[3] * scale, 0, false);
        outr[c >> 2] = (unsigned int)(lo & 0xFFFF) | ((unsigned int)hi << 16);
    }
}

// ---------------- fused dual MX-fp8 GEMM + softmax-stat tile kernel ----------------
// K=128 per mfma_scale (scales = 1.0) -> teacher 6 iters + student 4 iters.
// m97-style two-barrier K-loop. Frags assembled via shufflevector (register
// concat); af[4]=32 regs preloaded, bf streamed. acc(64)+frags(40)+addr(~30)
// fits the (256,3) ~170-VGPR cap.
// partials layout: [2*TJ][N][5] floats (Zt, V, UA, Zo, WB) per (slot,row).
// LDS: sA 16K + sB 16K + sW 16K = 48 KB -> 3 blocks/CU.
__launch_bounds__(256, 3)
__global__ void fused_kernel(const unsigned char* __restrict__ Xt,
                             const unsigned char* __restrict__ Xo,
                             float* __restrict__ partials) {
    __shared__ unsigned char sA[BM * 128];   // 16 KB (one 128x128B tile)
    __shared__ unsigned char sB[BN * 128];   // 16 KB
    __shared__ unsigned int  sW[16 * 256];   // 16 KB packed fp8 weights

    const int t = threadIdx.x, lane = t & 63, w = t >> 6;
    const int wm = w >> 1, wn = w & 1;
    const int lr = lane & 15, lg = lane >> 4;

    const int bid = blockIdx.x;
    const int tj = (bid & 7) | ((bid >> 9) << 3);
    const int ti = (bid >> 3) & 63;
    const int i0 = ti * BM, j0 = tj * BN;

    // staging: chunk m = (w*4+h)*64 + lane; row=m>>3, kc=(m&7)^(row&7)
    const int kc = (lane & 7) ^ (lane >> 3);
    int offT[4], offO[4], ldsOff[4];
    #pragma unroll
    for (int h = 0; h < 4; ++h) {
        const int row = (w * 4 + h) * 8 + (lane >> 3);
        offT[h]   = row * DT + kc * 16;
        offO[h]   = row * DO + kc * 16;
        ldsOff[h] = ((w * 4 + h) * 64 + lane) * 16;
    }
    const unsigned char* At = Xt + (size_t)i0 * DT;
    const unsigned char* Bt = Xt + (size_t)j0 * DT;
    const unsigned char* Ao = Xo + (size_t)i0 * DO;
    const unsigned char* Bo = Xo + (size_t)j0 * DO;

    // fragment ds_read addresses (loop-invariant); XOR swizzle: chunk^(row&7)
    int aoff[4][2], boff[4][2];
    #pragma unroll
    for (int mi = 0; mi < 4; ++mi) {
        const int rowA = wm * 64 + mi * 16 + lr;
        const int rowB = wn * 64 + mi * 16 + lr;
        #pragma unroll
        for (int s = 0; s < 2; ++s) {
            const int cc = ((lg * 2 + s) ^ (lr & 7)) * 16;
            aoff[mi][s] = rowA * 128 + cc;
            boff[mi][s] = rowB * 128 + cc;
        }
    }

    floatx4 acc[4][4];
    #pragma unroll
    for (int a = 0; a < 4; ++a)
        #pragma unroll
        for (int b = 0; b < 4; ++b)
            acc[a][b] = (floatx4){0.0f, 0.0f, 0.0f, 0.0f};

    // ---- teacher loop: 6 iterations of K=128 ----
    for (int kt = 0; kt < DT / 128; ++kt) {
        const int k0 = kt * 128;
        #pragma unroll
        for (int h = 0; h < 4; ++h) {
            gl2lds16(At + offT[h] + k0, sA + ldsOff[h]);
            gl2lds16(Bt + offT[h] + k0, sB + ldsOff[h]);
        }
        asm volatile("s_waitcnt vmcnt(0)" ::: "memory");
        __syncthreads();
        int32x8 af[4];
        #pragma unroll
        for (int mi = 0; mi < 4; ++mi)
            af[mi] = frag32(sA, aoff[mi][0], aoff[mi][1]);
        #pragma unroll
        for (int ni = 0; ni < 4; ++ni) {
            const int32x8 bfv = frag32(sB, boff[ni][0], boff[ni][1]);
            #pragma unroll
            for (int mi = 0; mi < 4; ++mi)
                acc[mi][ni] = __builtin_amdgcn_mfma_scale_f32_16x16x128_f8f6f4(
                    af[mi], bfv, acc[mi][ni],
                    0, 0,                      // cbsz=fp8, blgp=fp8
                    0, 0x7F7F7F7F,             // scale_a = 1.0 (e8m0 127)
                    0, 0x7F7F7F7F);            // scale_b = 1.0
        }
        __syncthreads();                       // frag reads done -> restage OK
    }

    // ---- teacher epilogue: Zt, V, UA per row; park W=e^3 as fp8 in sW ----
    // C/D layout (16x16 family, shape-determined): col=lane&15, row=lg*4+reg
    #pragma unroll
    for (int mi = 0; mi < 4; ++mi) {
        #pragma unroll
        for (int r = 0; r < 4; ++r) {
            const int row = wm * 64 + mi * 16 + lg * 4 + r;
            const int gi  = i0 + row;
            float zt = 0.0f, vv = 0.0f, ua = 0.0f, e3v[4];
            #pragma unroll
            for (int ni = 0; ni < 4; ++ni) {
                const int gj = j0 + wn * 64 + ni * 16 + lr;
                const float a = acc[mi][ni][r];
                float ea = __expf(a - 1.0f);
                if (gi == gj) ea = 0.0f;       // diagonal -> prob 0
                const float e3 = ea * ea * ea;
                zt += ea; vv += e3; ua += e3 * a; e3v[ni] = e3;
            }
            const int lo = __builtin_amdgcn_cvt_pk_fp8_f32(e3v[0], e3v[1], 0, false);
            const int hi = __builtin_amdgcn_cvt_pk_fp8_f32(e3v[2], e3v[3], 0, false);
            sW[(mi * 4 + r) * 256 + t] =
                (unsigned int)(lo & 0xFFFF) | ((unsigned int)hi << 16);
            #pragma unroll
            for (int m = 8; m >= 1; m >>= 1) {
                zt += __shfl_xor(zt, m);
                vv += __shfl_xor(vv, m);
                ua += __shfl_xor(ua, m);
            }
            if (lr == 0) {
                float* p = partials + ((size_t)(tj * 2 + wn) * N + gi) * 5;
                p[0] = zt; p[1] = vv; p[2] = ua;
            }
        }
    }

    // ---- student loop: 4 iterations of K=128 (same accumulators) ----
    #pragma unroll
    for (int a = 0; a < 4; ++a)
        #pragma unroll
        for (int b = 0; b < 4; ++b)
            acc[a][b] = (floatx4){0.0f, 0.0f, 0.0f, 0.0f};

    for (int ko = 0; ko < DO / 128; ++ko) {
        const int k0 = ko * 128;
        #pragma unroll
        for (int h = 0; h < 4; ++h) {
            gl2lds16(Ao + offO[h] + k0, sA + ldsOff[h]);
            gl2lds16(Bo + offO[h] + k0, sB + ldsOff[h]);
        }
        asm volatile("s_waitcnt vmcnt(0)" ::: "memory");
        __syncthreads();
        int32x8 af[4];
        #pragma unroll
        for (int mi = 0; mi < 4; ++mi)
            af[mi] = frag32(sA, aoff[mi][0], aoff[mi][1]);
        #pragma unroll
        for (int ni = 0; ni < 4; ++ni) {
            const int32x8 bfv = frag32(sB, boff[ni][0], boff[ni][1]);
            #pragma unroll
            for (int mi = 0; mi < 4; ++mi)
                acc[mi][ni] = __builtin_amdgcn_mfma_scale_f32_16x16x128_f8f6f4(
                    af[mi], bfv, acc[mi][ni],
                    0, 0, 0, 0x7F7F7F7F, 0, 0x7F7F7F7F);
        }
        __syncthreads();
    }

    // ---- student epilogue: Zo, WB per row ----
    #pragma unroll
    for (int mi = 0; mi < 4; ++mi) {
        #pragma unroll
        for (int r = 0; r < 4; ++r) {
            const int row = wm * 64 + mi * 16 + lg * 4 + r;
            const int gi  = i0 + row;
            const int w4  = (int)sW[(mi * 4 + r) * 256 + t];
            // byte-select must be an immediate: decode all four up front
            float wv[4];
            wv[0] = __builtin_amdgcn_cvt_f32_fp8(w4, 0);
            wv[1] = __builtin_amdgcn_cvt_f32_fp8(w4, 1);
            wv[2] = __builtin_amdgcn_cvt_f32_fp8(w4, 2);
            wv[3] = __builtin_amdgcn_cvt_f32_fp8(w4, 3);
            float zo = 0.0f, wb = 0.0f;
            #pragma unroll
            for (int ni = 0; ni < 4; ++ni) {
                const int gj = j0 + wn * 64 + ni * 16 + lr;
                const float b = acc[mi][ni][r];
                float eb = __expf(b - 1.0f);
                if (gi == gj) eb = 0.0f;
                zo += eb; wb += wv[ni] * b;    // diag: W==0 -> no contribution
            }
            #pragma unroll
            for (int m = 8; m >= 1; m >>= 1) {
                zo += __shfl_xor(zo, m);
                wb += __shfl_xor(wb, m);
            }
            if (lr == 0) {
                float* p = partials + ((size_t)(tj * 2 + wn) * N + gi) * 5;
                p[3] = zo; p[4] = wb;
            }
        }
    }
}

// ---------------- final per-row combine + scalar reduce ----------------
__global__ void reduce_kernel(const float* __restrict__ partials,
                              float* __restrict__ out) {
    const int i = blockIdx.x * 256 + threadIdx.x;   // row
    float zt = 0.0f, vv = 0.0f, ua = 0.0f, zo = 0.0f, wb = 0.0f;
    for (int jb = 0; jb < 2 * TJ; ++jb) {
        const float* p = partials + ((size_t)jb * N + i) * 5;
        zt += p[0]; vv += p[1]; ua += p[2]; zo += p[3]; wb += p[4];
    }
    // loss_i = (U + V*log(Zo/Zt)) / Zt^3, U = UA - WB
    float li = (ua - wb + vv * __logf(zo / zt)) / (zt * zt * zt);
    #pragma unroll
    for (int m = 32; m >= 1; m >>= 1) li += __shfl_xor(li, m);
    __shared__ float wsh[4];
    const int w = threadIdx.x >> 6;
    if ((threadIdx.x & 63) == 0) wsh[w] = li;
    __syncthreads();
    if (threadIdx.x == 0) {
        const float s = (wsh[0] + wsh[1] + wsh[2] + wsh[3]) *
                        (1.0f / ((float)N * (float)N));   // WEIGHT=1, mean over N^2
        atomicAdd(out, s);
    }
}

extern "C" void kernel_launch(void* const* d_in, const int* in_sizes, int n_in,
                              void* d_out, int out_size, void* d_ws, size_t ws_size,
                              hipStream_t stream) {
    (void)in_sizes; (void)n_in; (void)out_size; (void)ws_size;
    const float* mo = (const float*)d_in[0];   // model_output [8192,512] fp32
    const float* tg = (const float*)d_in[1];   // targets      [8192,768] fp32
    float* out = (float*)d_out;

    char* ws = (char*)d_ws;
    unsigned char* Xt = (unsigned char*)ws;                        // 8192*768 fp8 = 6.29 MB
    unsigned char* Xo = (unsigned char*)(ws + (size_t)N * DT);     // 8192*512 fp8 = 4.19 MB
    float* partials   = (float*)(ws + (size_t)N * DT + (size_t)N * DO);
    // partials: 128 * 8192 * 5 * 4 B = 20.97 MB; total ws ~31.5 MB

    norm_kernel<<<N / 4, 256, 0, stream>>>(tg, (unsigned int*)Xt, DT, out);  // also zeroes out
    norm_kernel<<<N / 4, 256, 0, stream>>>(mo, (unsigned int*)Xo, DO, nullptr);
    fused_kernel<<<TI * TJ, 256, 0, stream>>>(Xt, Xo, partials);
    reduce_kernel<<<N / 256, 256, 0, stream>>>(partials, out);
}

// Round 7
// 587.037 us; speedup vs baseline: 1.5688x; 1.5535x over previous
//
#include <hip/hip_runtime.h>

#define N    8192
#define DT   768
#define DO   512
#define BM   128
#define BN   128
#define TI   (N / BM)   // 64
#define TJ   (N / BN)   // 64

typedef __attribute__((ext_vector_type(8))) int    int32x8;
typedef __attribute__((ext_vector_type(4))) int    int32x4;
typedef __attribute__((ext_vector_type(4))) float  floatx4;

// async global->LDS, 16B per lane (global_load_lds_dwordx4)
__device__ inline void gl2lds16(const void* g, void* l) {
    __builtin_amdgcn_global_load_lds(
        (const __attribute__((address_space(1))) unsigned int*)g,
        (__attribute__((address_space(3))) unsigned int*)l, 16, 0, 0);
}

// register-only concat of two 16B LDS loads into one 32B frag
__device__ inline int32x8 frag32(const unsigned char* base, int off0, int off1) {
    const int32x4 lo = *(const int32x4*)(base + off0);
    const int32x4 hi = *(const int32x4*)(base + off1);
    return __builtin_shufflevector(lo, hi, 0, 1, 2, 3, 4, 5, 6, 7);
}

// ---------------- row-normalize fp32 -> fp8 e4m3 (one wave per row) ----------------
__global__ void norm_kernel(const float* __restrict__ X,
                            unsigned int* __restrict__ Xn, int D,
                            float* __restrict__ zero_me) {
    if (zero_me && blockIdx.x == 0 && threadIdx.x == 0) zero_me[0] = 0.0f;
    const int row  = blockIdx.x * 4 + (threadIdx.x >> 6);
    const int lane = threadIdx.x & 63;
    const float* xr = X + (size_t)row * D;
    float ss = 0.0f;
    for (int c = lane * 4; c < D; c += 256) {
        const floatx4 v = *(const floatx4*)(xr + c);
        ss += v[0] * v[0] + v[1] * v[1] + v[2] * v[2] + v[3] * v[3];
    }
    #pragma unroll
    for (int m = 32; m >= 1; m >>= 1) ss += __shfl_xor(ss, m);
    const float scale = 1.0f / fmaxf(sqrtf(ss), 1e-8f);
    unsigned int* outr = Xn + (size_t)row * (D / 4);
    for (int c = lane * 4; c < D; c += 256) {
        const floatx4 v = *(const floatx4*)(xr + c);
        const int lo = __builtin_amdgcn_cvt_pk_fp8_f32(v[0] * scale, v[1] * scale, 0, false);
        const int hi = __builtin_amdgcn_cvt_pk_fp8_f32(v[2] * scale, v[3] * scale, 0, false);
        outr[c >> 2] = (unsigned int)(lo & 0xFFFF) | ((unsigned int)hi << 16);
    }
}

// ---------------- fused dual MX-fp8 GEMM + softmax-stat tile kernel ----------------
// K=128 per mfma_scale (scales = 1.0) -> teacher 6 iters + student 4 iters.
// __launch_bounds__(256,2): the (256,3) cap (~168 unified regs) forced the
// allocator to spill acc/frags every iteration in R4-R6 -> 3.4 GB of scratch
// round-trip traffic = the entire 833 us runtime. fp8 v8i32 frags are 2x the
// bf16 v8i16 frags, which is why the same structure fit at (256,3) in R2.
// partials layout: [2*TJ][N][5] floats (Zt, V, UA, Zo, WB) per (slot,row).
// LDS: sA 16K + sB 16K + sW 16K = 48 KB.
__launch_bounds__(256, 2)
__global__ void fused_kernel(const unsigned char* __restrict__ Xt,
                             const unsigned char* __restrict__ Xo,
                             float* __restrict__ partials) {
    __shared__ unsigned char sA[BM * 128];   // 16 KB (one 128x128B tile)
    __shared__ unsigned char sB[BN * 128];   // 16 KB
    __shared__ unsigned int  sW[16 * 256];   // 16 KB packed fp8 weights

    const int t = threadIdx.x, lane = t & 63, w = t >> 6;
    const int wm = w >> 1, wn = w & 1;
    const int lr = lane & 15, lg = lane >> 4;

    const int bid = blockIdx.x;
    const int tj = (bid & 7) | ((bid >> 9) << 3);
    const int ti = (bid >> 3) & 63;
    const int i0 = ti * BM, j0 = tj * BN;

    // staging: chunk m = (w*4+h)*64 + lane; row=m>>3, kc=(m&7)^(row&7)
    const int kc = (lane & 7) ^ (lane >> 3);
    int offT[4], offO[4], ldsOff[4];
    #pragma unroll
    for (int h = 0; h < 4; ++h) {
        const int row = (w * 4 + h) * 8 + (lane >> 3);
        offT[h]   = row * DT + kc * 16;
        offO[h]   = row * DO + kc * 16;
        ldsOff[h] = ((w * 4 + h) * 64 + lane) * 16;
    }
    const unsigned char* At = Xt + (size_t)i0 * DT;
    const unsigned char* Bt = Xt + (size_t)j0 * DT;
    const unsigned char* Ao = Xo + (size_t)i0 * DO;
    const unsigned char* Bo = Xo + (size_t)j0 * DO;

    // fragment ds_read addresses (loop-invariant); XOR swizzle: chunk^(row&7)
    int aoff[4][2], boff[4][2];
    #pragma unroll
    for (int mi = 0; mi < 4; ++mi) {
        const int rowA = wm * 64 + mi * 16 + lr;
        const int rowB = wn * 64 + mi * 16 + lr;
        #pragma unroll
        for (int s = 0; s < 2; ++s) {
            const int cc = ((lg * 2 + s) ^ (lr & 7)) * 16;
            aoff[mi][s] = rowA * 128 + cc;
            boff[mi][s] = rowB * 128 + cc;
        }
    }

    floatx4 acc[4][4];
    #pragma unroll
    for (int a = 0; a < 4; ++a)
        #pragma unroll
        for (int b = 0; b < 4; ++b)
            acc[a][b] = (floatx4){0.0f, 0.0f, 0.0f, 0.0f};

    // ---- teacher loop: 6 iterations of K=128 ----
    for (int kt = 0; kt < DT / 128; ++kt) {
        const int k0 = kt * 128;
        #pragma unroll
        for (int h = 0; h < 4; ++h) {
            gl2lds16(At + offT[h] + k0, sA + ldsOff[h]);
            gl2lds16(Bt + offT[h] + k0, sB + ldsOff[h]);
        }
        asm volatile("s_waitcnt vmcnt(0)" ::: "memory");
        __syncthreads();
        int32x8 af[4];
        #pragma unroll
        for (int mi = 0; mi < 4; ++mi)
            af[mi] = frag32(sA, aoff[mi][0], aoff[mi][1]);
        #pragma unroll
        for (int ni = 0; ni < 4; ++ni) {
            const int32x8 bfv = frag32(sB, boff[ni][0], boff[ni][1]);
            #pragma unroll
            for (int mi = 0; mi < 4; ++mi)
                acc[mi][ni] = __builtin_amdgcn_mfma_scale_f32_16x16x128_f8f6f4(
                    af[mi], bfv, acc[mi][ni],
                    0, 0,                      // cbsz=fp8, blgp=fp8
                    0, 0x7F7F7F7F,             // scale_a = 1.0 (e8m0 127)
                    0, 0x7F7F7F7F);            // scale_b = 1.0
        }
        __syncthreads();                       // frag reads done -> restage OK
    }

    // ---- teacher epilogue: Zt, V, UA per row; park W=e^3 as fp8 in sW ----
    // C/D layout (16x16 family, shape-determined): col=lane&15, row=lg*4+reg
    #pragma unroll
    for (int mi = 0; mi < 4; ++mi) {
        #pragma unroll
        for (int r = 0; r < 4; ++r) {
            const int row = wm * 64 + mi * 16 + lg * 4 + r;
            const int gi  = i0 + row;
            float zt = 0.0f, vv = 0.0f, ua = 0.0f, e3v[4];
            #pragma unroll
            for (int ni = 0; ni < 4; ++ni) {
                const int gj = j0 + wn * 64 + ni * 16 + lr;
                const float a = acc[mi][ni][r];
                float ea = __expf(a - 1.0f);
                if (gi == gj) ea = 0.0f;       // diagonal -> prob 0
                const float e3 = ea * ea * ea;
                zt += ea; vv += e3; ua += e3 * a; e3v[ni] = e3;
            }
            const int lo = __builtin_amdgcn_cvt_pk_fp8_f32(e3v[0], e3v[1], 0, false);
            const int hi = __builtin_amdgcn_cvt_pk_fp8_f32(e3v[2], e3v[3], 0, false);
            sW[(mi * 4 + r) * 256 + t] =
                (unsigned int)(lo & 0xFFFF) | ((unsigned int)hi << 16);
            #pragma unroll
            for (int m = 8; m >= 1; m >>= 1) {
                zt += __shfl_xor(zt, m);
                vv += __shfl_xor(vv, m);
                ua += __shfl_xor(ua, m);
            }
            if (lr == 0) {
                float* p = partials + ((size_t)(tj * 2 + wn) * N + gi) * 5;
                p[0] = zt; p[1] = vv; p[2] = ua;
            }
        }
    }

    // ---- student loop: 4 iterations of K=128 (same accumulators) ----
    #pragma unroll
    for (int a = 0; a < 4; ++a)
        #pragma unroll
        for (int b = 0; b < 4; ++b)
            acc[a][b] = (floatx4){0.0f, 0.0f, 0.0f, 0.0f};

    for (int ko = 0; ko < DO / 128; ++ko) {
        const int k0 = ko * 128;
        #pragma unroll
        for (int h = 0; h < 4; ++h) {
            gl2lds16(Ao + offO[h] + k0, sA + ldsOff[h]);
            gl2lds16(Bo + offO[h] + k0, sB + ldsOff[h]);
        }
        asm volatile("s_waitcnt vmcnt(0)" ::: "memory");
        __syncthreads();
        int32x8 af[4];
        #pragma unroll
        for (int mi = 0; mi < 4; ++mi)
            af[mi] = frag32(sA, aoff[mi][0], aoff[mi][1]);
        #pragma unroll
        for (int ni = 0; ni < 4; ++ni) {
            const int32x8 bfv = frag32(sB, boff[ni][0], boff[ni][1]);
            #pragma unroll
            for (int mi = 0; mi < 4; ++mi)
                acc[mi][ni] = __builtin_amdgcn_mfma_scale_f32_16x16x128_f8f6f4(
                    af[mi], bfv, acc[mi][ni],
                    0, 0, 0, 0x7F7F7F7F, 0, 0x7F7F7F7F);
        }
        __syncthreads();
    }

    // ---- student epilogue: Zo, WB per row ----
    #pragma unroll
    for (int mi = 0; mi < 4; ++mi) {
        #pragma unroll
        for (int r = 0; r < 4; ++r) {
            const int row = wm * 64 + mi * 16 + lg * 4 + r;
            const int gi  = i0 + row;
            const int w4  = (int)sW[(mi * 4 + r) * 256 + t];
            // byte-select must be an immediate: decode all four up front
            float wv[4];
            wv[0] = __builtin_amdgcn_cvt_f32_fp8(w4, 0);
            wv[1] = __builtin_amdgcn_cvt_f32_fp8(w4, 1);
            wv[2] = __builtin_amdgcn_cvt_f32_fp8(w4, 2);
            wv[3] = __builtin_amdgcn_cvt_f32_fp8(w4, 3);
            float zo = 0.0f, wb = 0.0f;
            #pragma unroll
            for (int ni = 0; ni < 4; ++ni) {
                const int gj = j0 + wn * 64 + ni * 16 + lr;
                const float b = acc[mi][ni][r];
                float eb = __expf(b - 1.0f);
                if (gi == gj) eb = 0.0f;
                zo += eb; wb += wv[ni] * b;    // diag: W==0 -> no contribution
            }
            #pragma unroll
            for (int m = 8; m >= 1; m >>= 1) {
                zo += __shfl_xor(zo, m);
                wb += __shfl_xor(wb, m);
            }
            if (lr == 0) {
                float* p = partials + ((size_t)(tj * 2 + wn) * N + gi) * 5;
                p[3] = zo; p[4] = wb;
            }
        }
    }
}

// ---------------- final per-row combine + scalar reduce ----------------
__global__ void reduce_kernel(const float* __restrict__ partials,
                              float* __restrict__ out) {
    const int i = blockIdx.x * 256 + threadIdx.x;   // row
    float zt = 0.0f, vv = 0.0f, ua = 0.0f, zo = 0.0f, wb = 0.0f;
    for (int jb = 0; jb < 2 * TJ; ++jb) {
        const float* p = partials + ((size_t)jb * N + i) * 5;
        zt += p[0]; vv += p[1]; ua += p[2]; zo += p[3]; wb += p[4];
    }
    // loss_i = (U + V*log(Zo/Zt)) / Zt^3, U = UA - WB
    float li = (ua - wb + vv * __logf(zo / zt)) / (zt * zt * zt);
    #pragma unroll
    for (int m = 32; m >= 1; m >>= 1) li += __shfl_xor(li, m);
    __shared__ float wsh[4];
    const int w = threadIdx.x >> 6;
    if ((threadIdx.x & 63) == 0) wsh[w] = li;
    __syncthreads();
    if (threadIdx.x == 0) {
        const float s = (wsh[0] + wsh[1] + wsh[2] + wsh[3]) *
                        (1.0f / ((float)N * (float)N));   // WEIGHT=1, mean over N^2
        atomicAdd(out, s);
    }
}

extern "C" void kernel_launch(void* const* d_in, const int* in_sizes, int n_in,
                              void* d_out, int out_size, void* d_ws, size_t ws_size,
                              hipStream_t stream) {
    (void)in_sizes; (void)n_in; (void)out_size; (void)ws_size;
    const float* mo = (const float*)d_in[0];   // model_output [8192,512] fp32
    const float* tg = (const float*)d_in[1];   // targets      [8192,768] fp32
    float* out = (float*)d_out;

    char* ws = (char*)d_ws;
    unsigned char* Xt = (unsigned char*)ws;                        // 8192*768 fp8 = 6.29 MB
    unsigned char* Xo = (unsigned char*)(ws + (size_t)N * DT);     // 8192*512 fp8 = 4.19 MB
    float* partials   = (float*)(ws + (size_t)N * DT + (size_t)N * DO);
    // partials: 128 * 8192 * 5 * 4 B = 20.97 MB; total ws ~31.5 MB

    norm_kernel<<<N / 4, 256, 0, stream>>>(tg, (unsigned int*)Xt, DT, out);  // also zeroes out
    norm_kernel<<<N / 4, 256, 0, stream>>>(mo, (unsigned int*)Xo, DO, nullptr);
    fused_kernel<<<TI * TJ, 256, 0, stream>>>(Xt, Xo, partials);
    reduce_kernel<<<N / 256, 256, 0, stream>>>(partials, out);
}